// Round 1
// baseline (83.076 us; speedup 1.0000x reference)
//
#include <hip/hip_runtime.h>

#define DIM 256
#define L_ 128
#define TD 64
#define NVOCAB 150
#define NB 2048

// ---------------------------------------------------------------------------
// Kernel A: M[c][d] = (1/16) * sum_e Wq[e][c] * Wk[e][d]   (256x256)
//           plus per-vocab scalar tables:
//           rel_s[v] = 0.5 * dot(rel_emb_w[v], Wrp[0:64])
//           pos_s[v] = 0.5 * dot(pos_emb_w[v], Wrp[64:128])
// ---------------------------------------------------------------------------
__global__ __launch_bounds__(256) void prep_kernel(
    const float* __restrict__ Wk, const float* __restrict__ Wq,
    const float* __restrict__ Wrp,
    const float* __restrict__ rel_emb_w, const float* __restrict__ pos_emb_w,
    float* __restrict__ M, float* __restrict__ rel_s, float* __restrict__ pos_s)
{
    if (blockIdx.x == DIM) {
        int v = threadIdx.x;
        if (v < NVOCAB) {
            float sr = 0.f, sp = 0.f;
            for (int j = 0; j < TD; ++j) {
                sr = fmaf(rel_emb_w[v * TD + j], Wrp[j], sr);
                sp = fmaf(pos_emb_w[v * TD + j], Wrp[TD + j], sp);
            }
            rel_s[v] = 0.5f * sr;   // BETA folded in
            pos_s[v] = 0.5f * sp;
        }
        return;
    }
    int c = blockIdx.x;   // column of Wq
    int d = threadIdx.x;  // column of Wk
    float acc = 0.f;
    for (int e = 0; e < DIM; ++e)
        acc = fmaf(Wq[e * DIM + c], Wk[e * DIM + d], acc);
    M[c * DIM + d] = acc * (1.0f / 16.0f);   // temperature = sqrt(256) = 16
}

// ---------------------------------------------------------------------------
// Kernel B: qk[b][d] = sum_c hn[b][c] * M[c][d]   (2048x256 = hn @ M)
// 256 blocks x 256 threads, 8 hn-rows per block, M streamed from L2.
// ---------------------------------------------------------------------------
__global__ __launch_bounds__(256) void qk_kernel(
    const float* __restrict__ hn, const float* __restrict__ M,
    float* __restrict__ qk)
{
    __shared__ float hn_s[8][DIM];
    const int r0 = blockIdx.x * 8;
    const int t = threadIdx.x;
#pragma unroll
    for (int i = 0; i < 8; ++i)
        hn_s[i][t] = hn[(size_t)(r0 + i) * DIM + t];
    __syncthreads();
    float acc[8] = {0.f, 0.f, 0.f, 0.f, 0.f, 0.f, 0.f, 0.f};
    for (int c = 0; c < DIM; ++c) {
        float m = M[c * DIM + t];          // coalesced, L2-resident
#pragma unroll
        for (int r = 0; r < 8; ++r)
            acc[r] = fmaf(hn_s[r][c], m, acc[r]);   // LDS broadcast read
    }
#pragma unroll
    for (int r = 0; r < 8; ++r)
        qk[(size_t)(r0 + r) * DIM + t] = acc[r];
}

// ---------------------------------------------------------------------------
// Kernel C: one block per b. 512 threads = 8 waves.
// Wave w, lane c: loads rows {8k+w}, cols [4c,4c+4) of out[b] as float4,
// keeps the 128KB tile in registers (read HBM exactly once).
// logits -> bias/mask -> softmax over L=128 -> weighted row sum.
// ---------------------------------------------------------------------------
__global__ __launch_bounds__(512, 4) void attn_main(
    const float* __restrict__ outp, const float* __restrict__ qk,
    const int* __restrict__ pos_ind, const int* __restrict__ rel_dt,
    const float* __restrict__ rel_s, const float* __restrict__ pos_s,
    float* __restrict__ y)
{
    const int b = blockIdx.x;
    const int t = threadIdx.x;
    const int w = t >> 6;       // wave 0..7
    const int lane = t & 63;

    __shared__ float logits[L_];   // logits, then reused as softmax weights
    __shared__ float bias[L_];
    __shared__ float red[8][DIM];
    __shared__ float ms[2];

    // qk fragment for this lane's 4 columns (same 1KB per wave, L2 hit)
    const float4 q4 = *reinterpret_cast<const float4*>(qk + (size_t)b * DIM + lane * 4);

    // bias + pad mask per row
    if (t < L_) {
        int pi = pos_ind[(size_t)b * L_ + t];
        int rd = rel_dt[(size_t)b * L_ + t];
        bias[t] = (pi == 0) ? -1e30f : (rel_s[rd] + pos_s[pi]);
    }

    // ---- pass 1: coalesced load of out[b], partial dots ----
    const float4* src = reinterpret_cast<const float4*>(outp + (size_t)b * (L_ * DIM));
    float4 v[16];
    float p[16];
#pragma unroll
    for (int k = 0; k < 16; ++k) {
        v[k] = src[k * 512 + t];   // row 8k+w, cols 4*lane..4*lane+3
        p[k] = v[k].x * q4.x + v[k].y * q4.y + v[k].z * q4.z + v[k].w * q4.w;
    }
    // 64-lane butterfly reduce each of the 16 row-partials
#pragma unroll
    for (int k = 0; k < 16; ++k) {
#pragma unroll
        for (int off = 32; off > 0; off >>= 1)
            p[k] += __shfl_xor(p[k], off, 64);
    }
    if (lane == 0) {
#pragma unroll
        for (int k = 0; k < 16; ++k)
            logits[k * 8 + w] = p[k];
    }
    __syncthreads();
    if (t < L_) logits[t] += bias[t];
    __syncthreads();

    // ---- softmax stats (wave 0 only) ----
    if (w == 0) {
        float a = logits[lane];
        float c2 = logits[lane + 64];
        float mx = fmaxf(a, c2);
#pragma unroll
        for (int off = 32; off > 0; off >>= 1)
            mx = fmaxf(mx, __shfl_xor(mx, off, 64));
        float s = __expf(a - mx) + __expf(c2 - mx);
#pragma unroll
        for (int off = 32; off > 0; off >>= 1)
            s += __shfl_xor(s, off, 64);
        if (lane == 0) { ms[0] = mx; ms[1] = 1.0f / s; }
    }
    __syncthreads();
    const float mx = ms[0], inv_s = ms[1];
    if (t < L_) logits[t] = __expf(logits[t] - mx) * inv_s;   // weights
    __syncthreads();

    // ---- pass 2: weighted row-sum from registers ----
    float o0 = 0.f, o1 = 0.f, o2 = 0.f, o3 = 0.f;
#pragma unroll
    for (int k = 0; k < 16; ++k) {
        float wk = logits[k * 8 + w];   // broadcast read
        o0 = fmaf(wk, v[k].x, o0);
        o1 = fmaf(wk, v[k].y, o1);
        o2 = fmaf(wk, v[k].z, o2);
        o3 = fmaf(wk, v[k].w, o3);
    }
    *reinterpret_cast<float4*>(&red[w][lane * 4]) = make_float4(o0, o1, o2, o3);
    __syncthreads();

    if (t < DIM) {
        float s = 0.f;
#pragma unroll
        for (int ww = 0; ww < 8; ++ww)
            s += red[ww][t];           // stride-1 across lanes, conflict-free
        y[(size_t)b * DIM + t] = s;
    }
}

// ---------------------------------------------------------------------------
extern "C" void kernel_launch(void* const* d_in, const int* in_sizes, int n_in,
                              void* d_out, int out_size, void* d_ws, size_t ws_size,
                              hipStream_t stream)
{
    const float* out_t     = (const float*)d_in[0];  // [B, L, DIM]
    const float* hn        = (const float*)d_in[1];  // [B, DIM]
    const int*   pos_ind   = (const int*)  d_in[2];  // [B, L]
    const int*   rel_dt    = (const int*)  d_in[3];  // [B, L]
    // d_in[4] = abs_dt (unused by reference)
    const float* pos_emb_w = (const float*)d_in[5];  // [VOCAB, TD]
    const float* rel_emb_w = (const float*)d_in[6];  // [VOCAB, TD]
    const float* Wk        = (const float*)d_in[7];  // [DIM, DIM]
    const float* Wq        = (const float*)d_in[8];  // [DIM, DIM]
    const float* Wrp       = (const float*)d_in[9];  // [1, 2*TD]

    float* y = (float*)d_out;                        // [B, DIM] fp32

    // workspace layout (floats): M[65536] | qk[B*DIM] | rel_s[256] | pos_s[256]
    float* M     = (float*)d_ws;
    float* qk    = M + DIM * DIM;
    float* rel_s = qk + (size_t)NB * DIM;
    float* pos_s = rel_s + 256;

    prep_kernel<<<DIM + 1, 256, 0, stream>>>(Wk, Wq, Wrp, rel_emb_w, pos_emb_w,
                                             M, rel_s, pos_s);
    qk_kernel<<<NB / 8, 256, 0, stream>>>(hn, M, qk);
    attn_main<<<NB, 512, 0, stream>>>(out_t, qk, pos_ind, rel_dt, rel_s, pos_s, y);
}

// Round 2
// 78.506 us; speedup vs baseline: 1.0582x; 1.0582x over previous
//
#include <hip/hip_runtime.h>

#define DIM 256
#define L_ 128
#define TD 64
#define NVOCAB 150
#define NB 2048

// ---------------------------------------------------------------------------
// Kernel A: M[c][d] = (1/16) * sum_e Wq[e][c] * Wk[e][d]   (256x256)
//           plus per-vocab scalar tables (BETA=0.5 folded in):
//           rel_s[v] = 0.5 * dot(rel_emb_w[v], Wrp[0:64])
//           pos_s[v] = 0.5 * dot(pos_emb_w[v], Wrp[64:128])
// ---------------------------------------------------------------------------
__global__ __launch_bounds__(256) void prep_kernel(
    const float* __restrict__ Wk, const float* __restrict__ Wq,
    const float* __restrict__ Wrp,
    const float* __restrict__ rel_emb_w, const float* __restrict__ pos_emb_w,
    float* __restrict__ M, float* __restrict__ rel_s, float* __restrict__ pos_s)
{
    if (blockIdx.x == DIM) {
        int v = threadIdx.x;
        if (v < NVOCAB) {
            float sr = 0.f, sp = 0.f;
            for (int j = 0; j < TD; ++j) {
                sr = fmaf(rel_emb_w[v * TD + j], Wrp[j], sr);
                sp = fmaf(pos_emb_w[v * TD + j], Wrp[TD + j], sp);
            }
            rel_s[v] = 0.5f * sr;
            pos_s[v] = 0.5f * sp;
        }
        return;
    }
    int cc = blockIdx.x;
    int d  = threadIdx.x;
    float acc = 0.f;
    for (int e = 0; e < DIM; ++e)
        acc = fmaf(Wq[e * DIM + cc], Wk[e * DIM + d], acc);
    M[cc * DIM + d] = acc * (1.0f / 16.0f);   // temperature = sqrt(256) = 16
}

// ---------------------------------------------------------------------------
// Kernel B (fused): blocks [0,256): qk = hn @ M.
//                   blocks [256,1280): bias_g[b*L+l] = mask ? -1e30 : rel+pos
// ---------------------------------------------------------------------------
__global__ __launch_bounds__(256) void qk_bias_kernel(
    const float* __restrict__ hn, const float* __restrict__ M,
    const int* __restrict__ pos_ind, const int* __restrict__ rel_dt,
    const float* __restrict__ rel_s, const float* __restrict__ pos_s,
    float* __restrict__ qk, float* __restrict__ bias_g)
{
    const int t = threadIdx.x;
    if (blockIdx.x >= NB / 8) {
        int idx = (blockIdx.x - NB / 8) * 256 + t;   // [0, NB*L_) exactly
        int pi = pos_ind[idx];
        int rd = rel_dt[idx];
        bias_g[idx] = (pi == 0) ? -1e30f : (rel_s[rd] + pos_s[pi]);
        return;
    }
    __shared__ float hn_s[8][DIM];
    const int r0 = blockIdx.x * 8;
#pragma unroll
    for (int i = 0; i < 8; ++i)
        hn_s[i][t] = hn[(size_t)(r0 + i) * DIM + t];
    __syncthreads();
    float acc[8] = {0.f, 0.f, 0.f, 0.f, 0.f, 0.f, 0.f, 0.f};
    for (int c = 0; c < DIM; ++c) {
        float m = M[c * DIM + t];
#pragma unroll
        for (int r = 0; r < 8; ++r)
            acc[r] = fmaf(hn_s[r][c], m, acc[r]);
    }
#pragma unroll
    for (int r = 0; r < 8; ++r)
        qk[(size_t)(r0 + r) * DIM + t] = acc[r];
}

// ---------------------------------------------------------------------------
// Kernel C: one block per b, 512 threads = 8 waves.
// Wave w owns rows [16w,16w+16). Lane = g*16+c: group g handles row
// 16w+4k+g at chunk k; lane c holds cols {64j+4c+i}.
// Per-group online softmax, no barriers in the hot loop, double-buffered
// prefetch. Final softmax-merge of the 32 group states through LDS.
// ---------------------------------------------------------------------------
__device__ __forceinline__ float dot4(float4 a, float4 b) {
    return fmaf(a.x, b.x, fmaf(a.y, b.y, fmaf(a.z, b.z, a.w * b.w)));
}

__global__ __launch_bounds__(512, 4) void attn_main(
    const float* __restrict__ outp, const float* __restrict__ qk,
    const float* __restrict__ bias_g, float* __restrict__ y)
{
    const int b    = blockIdx.x;
    const int t    = threadIdx.x;
    const int w    = t >> 6;
    const int lane = t & 63;
    const int g    = lane >> 4;
    const int c    = lane & 15;
    const int grp  = (w << 2) | g;

    __shared__ float mG[32];
    __shared__ float dG[32];
    __shared__ float red[32][DIM];

    // float4 view of out[b]: index (row, j, c) -> row*64 + j*16 + c
    const float4* __restrict__ src = (const float4*)outp + (size_t)b * (L_ * 64);
    const int r0   = (w << 4) | g;        // row of chunk 0 for this group
    const int base = r0 * 64 + c;

    // prefetch chunks 0 and 1 (rows r0, r0+4)
    float4 X0 = src[base +   0], X1 = src[base +  16], X2 = src[base +  32], X3 = src[base +  48];
    float4 Y0 = src[base + 256], Y1 = src[base + 272], Y2 = src[base + 288], Y3 = src[base + 304];

    // qk fragment for this lane's 16 columns
    const float4* __restrict__ qp = (const float4*)qk + (size_t)b * 64;
    const float4 q0 = qp[c], q1 = qp[c + 16], q2 = qp[c + 32], q3 = qp[c + 48];

    // biases for this group's 4 rows (broadcast across the 16 lanes, L2-hot)
    const float* __restrict__ bp = bias_g + (size_t)b * L_ + r0;
    const float bi0 = bp[0], bi1 = bp[4], bi2 = bp[8], bi3 = bp[12];

    float m = -1e30f, d = 0.f;
    float4 o0 = {0,0,0,0}, o1 = {0,0,0,0}, o2 = {0,0,0,0}, o3 = {0,0,0,0};

#define PROC(A0, A1, A2, A3, BI) do {                                        \
        float p = dot4(A0, q0) + dot4(A1, q1) + dot4(A2, q2) + dot4(A3, q3); \
        p += __shfl_xor(p, 1);                                               \
        p += __shfl_xor(p, 2);                                               \
        p += __shfl_xor(p, 4);                                               \
        p += __shfl_xor(p, 8);                                               \
        float logit = p + (BI);                                              \
        float mn = fmaxf(m, logit);                                          \
        float sc = __expf(m - mn);                                           \
        float we = __expf(logit - mn);                                       \
        d = d * sc + we;                                                     \
        m = mn;                                                              \
        o0.x = fmaf(we, A0.x, o0.x * sc); o0.y = fmaf(we, A0.y, o0.y * sc);  \
        o0.z = fmaf(we, A0.z, o0.z * sc); o0.w = fmaf(we, A0.w, o0.w * sc);  \
        o1.x = fmaf(we, A1.x, o1.x * sc); o1.y = fmaf(we, A1.y, o1.y * sc);  \
        o1.z = fmaf(we, A1.z, o1.z * sc); o1.w = fmaf(we, A1.w, o1.w * sc);  \
        o2.x = fmaf(we, A2.x, o2.x * sc); o2.y = fmaf(we, A2.y, o2.y * sc);  \
        o2.z = fmaf(we, A2.z, o2.z * sc); o2.w = fmaf(we, A2.w, o2.w * sc);  \
        o3.x = fmaf(we, A3.x, o3.x * sc); o3.y = fmaf(we, A3.y, o3.y * sc);  \
        o3.z = fmaf(we, A3.z, o3.z * sc); o3.w = fmaf(we, A3.w, o3.w * sc);  \
    } while (0)

    // chunk 0, prefetch chunk 2
    PROC(X0, X1, X2, X3, bi0);
    X0 = src[base + 512]; X1 = src[base + 528]; X2 = src[base + 544]; X3 = src[base + 560];
    // chunk 1, prefetch chunk 3
    PROC(Y0, Y1, Y2, Y3, bi1);
    Y0 = src[base + 768]; Y1 = src[base + 784]; Y2 = src[base + 800]; Y3 = src[base + 816];
    // chunks 2 and 3
    PROC(X0, X1, X2, X3, bi2);
    PROC(Y0, Y1, Y2, Y3, bi3);
#undef PROC

    // ---- merge the 32 per-group online-softmax states ----
    if (c == 0) { mG[grp] = m; dG[grp] = d; }
    __syncthreads();

    float M2 = -1e30f;
#pragma unroll
    for (int i = 0; i < 32; ++i) M2 = fmaxf(M2, mG[i]);
    float D = 0.f;
#pragma unroll
    for (int i = 0; i < 32; ++i) D += __expf(mG[i] - M2) * dG[i];
    const float f = __expf(m - M2) / D;

    float4* rw = (float4*)(&red[grp][0]);
    rw[c]      = make_float4(o0.x * f, o0.y * f, o0.z * f, o0.w * f);
    rw[c + 16] = make_float4(o1.x * f, o1.y * f, o1.z * f, o1.w * f);
    rw[c + 32] = make_float4(o2.x * f, o2.y * f, o2.z * f, o2.w * f);
    rw[c + 48] = make_float4(o3.x * f, o3.y * f, o3.z * f, o3.w * f);
    __syncthreads();

    if (t < DIM) {
        float s = 0.f;
#pragma unroll
        for (int gg = 0; gg < 32; ++gg) s += red[gg][t];
        y[(size_t)b * DIM + t] = s;
    }
}

// ---------------------------------------------------------------------------
extern "C" void kernel_launch(void* const* d_in, const int* in_sizes, int n_in,
                              void* d_out, int out_size, void* d_ws, size_t ws_size,
                              hipStream_t stream)
{
    const float* out_t     = (const float*)d_in[0];  // [B, L, DIM]
    const float* hn        = (const float*)d_in[1];  // [B, DIM]
    const int*   pos_ind   = (const int*)  d_in[2];  // [B, L]
    const int*   rel_dt    = (const int*)  d_in[3];  // [B, L]
    // d_in[4] = abs_dt (unused)
    const float* pos_emb_w = (const float*)d_in[5];  // [VOCAB, TD]
    const float* rel_emb_w = (const float*)d_in[6];  // [VOCAB, TD]
    const float* Wk        = (const float*)d_in[7];  // [DIM, DIM]
    const float* Wq        = (const float*)d_in[8];  // [DIM, DIM]
    const float* Wrp       = (const float*)d_in[9];  // [1, 2*TD]

    float* y = (float*)d_out;                        // [B, DIM] fp32

    // ws layout (floats): M[65536] | qk[B*DIM] | rel_s[256] | pos_s[256] | bias_g[B*L]
    float* M      = (float*)d_ws;
    float* qk     = M + DIM * DIM;
    float* rel_s  = qk + (size_t)NB * DIM;
    float* pos_s  = rel_s + 256;
    float* bias_g = pos_s + 256;

    prep_kernel<<<DIM + 1, 256, 0, stream>>>(Wk, Wq, Wrp, rel_emb_w, pos_emb_w,
                                             M, rel_s, pos_s);
    qk_bias_kernel<<<NB / 8 + (NB * L_) / 256, 256, 0, stream>>>(
        hn, M, pos_ind, rel_dt, rel_s, pos_s, qk, bias_g);
    attn_main<<<NB, 512, 0, stream>>>(out_t, qk, bias_g, y);
}

// Round 3
// 70.786 us; speedup vs baseline: 1.1736x; 1.1091x over previous
//
#include <hip/hip_runtime.h>

#define DIM 256
#define L_ 128
#define TD 64
#define NVOCAB 150
#define NB 2048

// ---------------------------------------------------------------------------
// Kernel A: M[c][d] = (1/16) * sum_e Wq[e][c] * Wk[e][d]   (256x256)
//           plus per-vocab scalar tables (BETA=0.5 folded in):
//           rel_s[v] = 0.5 * dot(rel_emb_w[v], Wrp[0:64])
//           pos_s[v] = 0.5 * dot(pos_emb_w[v], Wrp[64:128])
// ---------------------------------------------------------------------------
__global__ __launch_bounds__(256) void prep_kernel(
    const float* __restrict__ Wk, const float* __restrict__ Wq,
    const float* __restrict__ Wrp,
    const float* __restrict__ rel_emb_w, const float* __restrict__ pos_emb_w,
    float* __restrict__ M, float* __restrict__ rel_s, float* __restrict__ pos_s)
{
    if (blockIdx.x == DIM) {
        int v = threadIdx.x;
        if (v < NVOCAB) {
            float sr = 0.f, sp = 0.f;
#pragma unroll 8
            for (int j = 0; j < TD; ++j) {
                sr = fmaf(rel_emb_w[v * TD + j], Wrp[j], sr);
                sp = fmaf(pos_emb_w[v * TD + j], Wrp[TD + j], sp);
            }
            rel_s[v] = 0.5f * sr;
            pos_s[v] = 0.5f * sp;
        }
        return;
    }
    int cc = blockIdx.x;
    int d  = threadIdx.x;
    float acc = 0.f;
#pragma unroll 8
    for (int e = 0; e < DIM; ++e)
        acc = fmaf(Wq[e * DIM + cc], Wk[e * DIM + d], acc);
    M[cc * DIM + d] = acc * (1.0f / 16.0f);   // temperature = sqrt(256) = 16
}

// ---------------------------------------------------------------------------
// Kernel B (fused): blocks [0,256): qk = hn @ M.
//                   blocks [256,1280): bias_g[b*L+l] = mask ? -1e30 : rel+pos
// ---------------------------------------------------------------------------
__global__ __launch_bounds__(256) void qk_bias_kernel(
    const float* __restrict__ hn, const float* __restrict__ M,
    const int* __restrict__ pos_ind, const int* __restrict__ rel_dt,
    const float* __restrict__ rel_s, const float* __restrict__ pos_s,
    float* __restrict__ qk, float* __restrict__ bias_g)
{
    const int t = threadIdx.x;
    if (blockIdx.x >= NB / 8) {
        int idx = (blockIdx.x - NB / 8) * 256 + t;   // [0, NB*L_) exactly
        int pi = pos_ind[idx];
        int rd = rel_dt[idx];
        bias_g[idx] = (pi == 0) ? -1e30f : (rel_s[rd] + pos_s[pi]);
        return;
    }
    __shared__ float hn_s[8][DIM];
    const int r0 = blockIdx.x * 8;
#pragma unroll
    for (int i = 0; i < 8; ++i)
        hn_s[i][t] = hn[(size_t)(r0 + i) * DIM + t];
    __syncthreads();
    float acc[8] = {0.f, 0.f, 0.f, 0.f, 0.f, 0.f, 0.f, 0.f};
#pragma unroll 8
    for (int c = 0; c < DIM; ++c) {
        float m = M[c * DIM + t];
#pragma unroll
        for (int r = 0; r < 8; ++r)
            acc[r] = fmaf(hn_s[r][c], m, acc[r]);
    }
#pragma unroll
    for (int r = 0; r < 8; ++r)
        qk[(size_t)(r0 + r) * DIM + t] = acc[r];
}

// ---------------------------------------------------------------------------
// Kernel C: one block per b, 512 threads = 8 waves, 32 groups of 16 lanes.
// Group grp = 4w+g owns rows {r0+4k, k=0..3}, r0 = 16w+g; lane c holds
// 16 columns. ALL 16 float4 loads issue up-front (no register reuse, max
// MLP); 4 logit shfl-chains overlap via ILP; one max; single weighted
// accumulate (no online rescale). Merge of 32 group states through LDS.
// ---------------------------------------------------------------------------
__device__ __forceinline__ float dot4(float4 a, float4 b) {
    return fmaf(a.x, b.x, fmaf(a.y, b.y, fmaf(a.z, b.z, a.w * b.w)));
}

__global__ __launch_bounds__(512, 4) void attn_main(
    const float* __restrict__ outp, const float* __restrict__ qk,
    const float* __restrict__ bias_g, float* __restrict__ y)
{
    const int b    = blockIdx.x;
    const int t    = threadIdx.x;
    const int w    = t >> 6;
    const int lane = t & 63;
    const int g    = lane >> 4;
    const int c    = lane & 15;
    const int grp  = (w << 2) | g;

    __shared__ float mG[32];
    __shared__ float dG[32];
    __shared__ float red[32][DIM];

    // float4 view of out[b]: (row, j, c) -> row*64 + j*16 + c
    const float4* __restrict__ src = (const float4*)outp + (size_t)b * (L_ * 64);
    const int r0   = (w << 4) | g;
    const int base = r0 * 64 + c;

    // ---- issue ALL data loads immediately: rows r0+4k, col-blocks j ----
    float4 v[16];
#pragma unroll
    for (int k = 0; k < 4; ++k)
#pragma unroll
        for (int j = 0; j < 4; ++j)
            v[k * 4 + j] = src[base + k * 256 + j * 16];

    // qk fragment (L2-hot) and this group's 4 row biases
    const float4* __restrict__ qp = (const float4*)qk + (size_t)b * 64;
    float4 q[4];
#pragma unroll
    for (int j = 0; j < 4; ++j) q[j] = qp[c + j * 16];
    const float* __restrict__ bp = bias_g + (size_t)b * L_ + r0;
    float bi[4];
#pragma unroll
    for (int k = 0; k < 4; ++k) bi[k] = bp[4 * k];

    // ---- 4 logits: partial dots + 16-lane allreduce (chains overlap) ----
    float lg[4];
#pragma unroll
    for (int k = 0; k < 4; ++k) {
        float p = dot4(v[k * 4 + 0], q[0]) + dot4(v[k * 4 + 1], q[1]) +
                  dot4(v[k * 4 + 2], q[2]) + dot4(v[k * 4 + 3], q[3]);
        p += __shfl_xor(p, 1);
        p += __shfl_xor(p, 2);
        p += __shfl_xor(p, 4);
        p += __shfl_xor(p, 8);
        lg[k] = p + bi[k];
    }

    // ---- group-local softmax (plain, no online rescale) ----
    const float m = fmaxf(fmaxf(lg[0], lg[1]), fmaxf(lg[2], lg[3]));
    float we[4];
    float d = 0.f;
#pragma unroll
    for (int k = 0; k < 4; ++k) { we[k] = __expf(lg[k] - m); d += we[k]; }

    // ---- single weighted accumulate ----
    float4 o[4];
#pragma unroll
    for (int j = 0; j < 4; ++j) o[j] = make_float4(0.f, 0.f, 0.f, 0.f);
#pragma unroll
    for (int k = 0; k < 4; ++k)
#pragma unroll
        for (int j = 0; j < 4; ++j) {
            o[j].x = fmaf(we[k], v[k * 4 + j].x, o[j].x);
            o[j].y = fmaf(we[k], v[k * 4 + j].y, o[j].y);
            o[j].z = fmaf(we[k], v[k * 4 + j].z, o[j].z);
            o[j].w = fmaf(we[k], v[k * 4 + j].w, o[j].w);
        }

    // ---- merge 32 group states ----
    if (c == 0) { mG[grp] = m; dG[grp] = d; }
    __syncthreads();

    float Mx = -1e30f;
#pragma unroll
    for (int i = 0; i < 32; ++i) Mx = fmaxf(Mx, mG[i]);   // LDS broadcasts
    float term = (lane < 32) ? __expf(mG[lane] - Mx) * dG[lane] : 0.f;
#pragma unroll
    for (int off = 32; off >= 1; off >>= 1) term += __shfl_xor(term, off, 64);
    const float f = __expf(m - Mx) / term;

    float4* rw = (float4*)(&red[grp][0]);
#pragma unroll
    for (int j = 0; j < 4; ++j)
        rw[c + j * 16] = make_float4(o[j].x * f, o[j].y * f, o[j].z * f, o[j].w * f);
    __syncthreads();

    if (t < DIM) {
        float s = 0.f;
#pragma unroll
        for (int gg = 0; gg < 32; ++gg) s += red[gg][t];   // 2-way banked, free
        y[(size_t)b * DIM + t] = s;
    }
}

// ---------------------------------------------------------------------------
extern "C" void kernel_launch(void* const* d_in, const int* in_sizes, int n_in,
                              void* d_out, int out_size, void* d_ws, size_t ws_size,
                              hipStream_t stream)
{
    const float* out_t     = (const float*)d_in[0];  // [B, L, DIM]
    const float* hn        = (const float*)d_in[1];  // [B, DIM]
    const int*   pos_ind   = (const int*)  d_in[2];  // [B, L]
    const int*   rel_dt    = (const int*)  d_in[3];  // [B, L]
    // d_in[4] = abs_dt (unused)
    const float* pos_emb_w = (const float*)d_in[5];  // [VOCAB, TD]
    const float* rel_emb_w = (const float*)d_in[6];  // [VOCAB, TD]
    const float* Wk        = (const float*)d_in[7];  // [DIM, DIM]
    const float* Wq        = (const float*)d_in[8];  // [DIM, DIM]
    const float* Wrp       = (const float*)d_in[9];  // [1, 2*TD]

    float* y = (float*)d_out;                        // [B, DIM] fp32

    // ws layout (floats): M[65536] | qk[B*DIM] | rel_s[256] | pos_s[256] | bias_g[B*L]
    float* M      = (float*)d_ws;
    float* qk     = M + DIM * DIM;
    float* rel_s  = qk + (size_t)NB * DIM;
    float* pos_s  = rel_s + 256;
    float* bias_g = pos_s + 256;

    prep_kernel<<<DIM + 1, 256, 0, stream>>>(Wk, Wq, Wrp, rel_emb_w, pos_emb_w,
                                             M, rel_s, pos_s);
    qk_bias_kernel<<<NB / 8 + (NB * L_) / 256, 256, 0, stream>>>(
        hn, M, pos_ind, rel_dt, rel_s, pos_s, qk, bias_g);
    attn_main<<<NB, 512, 0, stream>>>(out_t, qk, bias_g, y);
}